// Round 1
// baseline (467.438 us; speedup 1.0000x reference)
//
#include <hip/hip_runtime.h>

#define SEQ   2048
#define EMB   2048
#define NHEAD 16
#define HDIM  128
#define ROWSM 4096  // B*SEQ

typedef float  f32x4  __attribute__((ext_vector_type(4)));
typedef __bf16 bf16x8 __attribute__((ext_vector_type(8)));

__device__ __forceinline__ unsigned short f2bf(float f) {
  union { float f; unsigned int u; } v; v.f = f;
  return (unsigned short)((v.u + 0x7fffu + ((v.u >> 16) & 1u)) >> 16);
}

__device__ __forceinline__ void gload16(const void* g, void* l) {
  __builtin_amdgcn_global_load_lds(
      (__attribute__((address_space(1))) const unsigned int*)g,
      (__attribute__((address_space(3))) unsigned int*)l,
      16, 0, 0);
}

// fp32 -> bf16 bulk convert, 4 elems/thread
__global__ void cvt_bf16(const float* __restrict__ in,
                         unsigned short* __restrict__ out, int n4) {
  int i = blockIdx.x * 256 + threadIdx.x;
  if (i >= n4) return;
  float4 v = ((const float4*)in)[i];
  ushort4 o;
  o.x = f2bf(v.x); o.y = f2bf(v.y); o.z = f2bf(v.z); o.w = f2bf(v.w);
  ((ushort4*)out)[i] = o;
}

// C = A @ B^T. A: MxK bf16 row-major, B: NxK bf16 row-major.
// STORE_F32=0: C bf16; STORE_F32=1: C fp32 + bias.
template <int STORE_F32>
__global__ __launch_bounds__(256, 2) void gemm_nt(
    const unsigned short* __restrict__ A, const unsigned short* __restrict__ B,
    void* __restrict__ Cout, const float* __restrict__ bias,
    int M, int N, int K) {
  __shared__ __align__(16) unsigned short As[128 * 64];
  __shared__ __align__(16) unsigned short Bs[128 * 64];
  const int tid  = threadIdx.x;
  const int lane = tid & 63;
  const int w    = tid >> 6;
  const int m0 = blockIdx.y * 128;
  const int n0 = blockIdx.x * 128;
  const int wm = (w >> 1) * 64;
  const int wn = (w & 1) * 64;
  const int lg = lane >> 4;
  const int lc = lane & 15;

  f32x4 acc[4][4] = {};

  const int srow = lane >> 3;        // 0..7 row within 1KB chunk (8 rows x 128B)
  const int scol = (lane & 7) * 8;   // element col within row

  for (int k0 = 0; k0 < K; k0 += 64) {
    if (k0) __syncthreads();
#pragma unroll
    for (int ii = 0; ii < 4; ++ii) {
      int i = w * 4 + ii;            // 16 chunks of 1KB each per tile
      int r = i * 8 + srow;
      gload16(A + (size_t)(m0 + r) * K + k0 + scol, (char*)As + i * 1024);
      gload16(B + (size_t)(n0 + r) * K + k0 + scol, (char*)Bs + i * 1024);
    }
    __syncthreads();
#pragma unroll
    for (int kk = 0; kk < 2; ++kk) {
      const int co = kk * 32 + lg * 8;
      bf16x8 a[4], b[4];
#pragma unroll
      for (int i = 0; i < 4; ++i)
        a[i] = *(const bf16x8*)(As + (wm + i * 16 + lc) * 64 + co);
#pragma unroll
      for (int j = 0; j < 4; ++j)
        b[j] = *(const bf16x8*)(Bs + (wn + j * 16 + lc) * 64 + co);
#pragma unroll
      for (int i = 0; i < 4; ++i)
#pragma unroll
        for (int j = 0; j < 4; ++j)
          acc[i][j] = __builtin_amdgcn_mfma_f32_16x16x32_bf16(a[i], b[j], acc[i][j], 0, 0, 0);
    }
  }

  const int rb = lg * 4;
#pragma unroll
  for (int i = 0; i < 4; ++i) {
#pragma unroll
    for (int j = 0; j < 4; ++j) {
      int col = n0 + wn + j * 16 + lc;
#pragma unroll
      for (int r = 0; r < 4; ++r) {
        int row = m0 + wm + i * 16 + rb + r;
        if (STORE_F32) {
          ((float*)Cout)[(size_t)row * N + col] = acc[i][j][r] + bias[col];
        } else {
          ((unsigned short*)Cout)[(size_t)row * N + col] = f2bf(acc[i][j][r]);
        }
      }
    }
  }
}

// Causal flash attention. Grid: (SEQ/128, B*H). Block: 256 (4 waves x 32 q-rows).
// Head blocks are contiguous TxD slices of the flat projection buffers.
__global__ __launch_bounds__(256, 2) void attn_causal(
    const unsigned short* __restrict__ Pq, const unsigned short* __restrict__ Pk,
    const unsigned short* __restrict__ Pv, unsigned short* __restrict__ ctx) {
  __shared__ __align__(16) unsigned short Ks[64 * 128];   // K tile [kv][d]
  __shared__ __align__(16) unsigned short Vt[128 * 64];   // V tile transposed [d][kv]
  __shared__ __align__(16) unsigned short Ps[4][32 * 64]; // per-wave P [qrow][kv]

  const int tid  = threadIdx.x;
  const int lane = tid & 63;
  const int w    = tid >> 6;
  const int lg   = lane >> 4;
  const int lc   = lane & 15;

  const int bh = blockIdx.y;   // b*16 + h
  const int b  = bh >> 4;
  const int h  = bh & 15;
  const int q0 = blockIdx.x * 128;
  const int qw = q0 + w * 32;

  const size_t hoff = (size_t)bh * SEQ * HDIM;
  const unsigned short* Q  = Pq + hoff;
  const unsigned short* Kh = Pk + hoff;
  const unsigned short* Vh = Pv + hoff;

  // Q fragments: A-layout row=lane&15, k = kk*32 + (lane>>4)*8 + j
  bf16x8 aq[2][4];
#pragma unroll
  for (int mt = 0; mt < 2; ++mt)
#pragma unroll
    for (int kk = 0; kk < 4; ++kk)
      aq[mt][kk] = *(const bf16x8*)(Q + (size_t)(qw + mt * 16 + lc) * HDIM + kk * 32 + lg * 8);

  const float NEG = -3.0e38f;
  float m_r[2][4], l_r[2][4];
  f32x4 o[2][8] = {};
#pragma unroll
  for (int mt = 0; mt < 2; ++mt)
#pragma unroll
    for (int r = 0; r < 4; ++r) { m_r[mt][r] = NEG; l_r[mt][r] = 0.f; }

  const float Cs = 0.12753123161692858f;  // log2(e)/sqrt(128)

  const int ntiles = q0 / 64 + 2;
  for (int t = 0; t < ntiles; ++t) {
    const int kv0 = t * 64;
    if (t) __syncthreads();
    // stage K linear via global_load_lds: 16 chunks of 1KB (4 rows of 256B each)
#pragma unroll
    for (int ii = 0; ii < 4; ++ii) {
      int i = w * 4 + ii;
      int r = i * 4 + lg;
      gload16(Kh + (size_t)(kv0 + r) * HDIM + lc * 8, (char*)Ks + i * 1024);
    }
    // stage V transposed (register path): unit = 2 kv rows x 8 d elems
#pragma unroll
    for (int uu = 0; uu < 2; ++uu) {
      int u = tid + uu * 256;
      int kp = u >> 4, dg = u & 15;
      int k = kp * 2, d0 = dg * 8;
      uint4 r0 = *(const uint4*)(Vh + (size_t)(kv0 + k) * HDIM + d0);
      uint4 r1 = *(const uint4*)(Vh + (size_t)(kv0 + k + 1) * HDIM + d0);
      const unsigned short* e0 = (const unsigned short*)&r0;
      const unsigned short* e1 = (const unsigned short*)&r1;
#pragma unroll
      for (int j = 0; j < 8; ++j)
        *(unsigned int*)&Vt[(d0 + j) * 64 + k] =
            (unsigned int)e0[j] | ((unsigned int)e1[j] << 16);
    }
    __syncthreads();

    if (kv0 <= qw + 31) {  // wave-uniform: skip fully-masked tiles
      // S = Q @ K^T (NT form)
      f32x4 s[2][4] = {};
#pragma unroll
      for (int kk = 0; kk < 4; ++kk) {
        bf16x8 bk[4];
#pragma unroll
        for (int nt = 0; nt < 4; ++nt)
          bk[nt] = *(const bf16x8*)(Ks + (nt * 16 + lc) * 128 + kk * 32 + lg * 8);
#pragma unroll
        for (int mt = 0; mt < 2; ++mt)
#pragma unroll
          for (int nt = 0; nt < 4; ++nt)
            s[mt][nt] = __builtin_amdgcn_mfma_f32_16x16x32_bf16(aq[mt][kk], bk[nt], s[mt][nt], 0, 0, 0);
      }
      // causal mask (only when the tile touches the diagonal)
      if (kv0 + 63 > qw) {
#pragma unroll
        for (int mt = 0; mt < 2; ++mt)
#pragma unroll
          for (int r = 0; r < 4; ++r) {
            int row = qw + mt * 16 + lg * 4 + r;
#pragma unroll
            for (int nt = 0; nt < 4; ++nt) {
              int col = kv0 + nt * 16 + lc;
              if (col > row) s[mt][nt][r] = NEG;
            }
          }
      }
      // online softmax; row lives across 16 lanes of the same l>>4 group
#pragma unroll
      for (int mt = 0; mt < 2; ++mt) {
#pragma unroll
        for (int r = 0; r < 4; ++r) {
          float rm = fmaxf(fmaxf(s[mt][0][r], s[mt][1][r]),
                           fmaxf(s[mt][2][r], s[mt][3][r]));
          rm = fmaxf(rm, __shfl_xor(rm, 1));
          rm = fmaxf(rm, __shfl_xor(rm, 2));
          rm = fmaxf(rm, __shfl_xor(rm, 4));
          rm = fmaxf(rm, __shfl_xor(rm, 8));
          float mnew = fmaxf(m_r[mt][r], rm);
          float alpha = exp2f((m_r[mt][r] - mnew) * Cs);
          m_r[mt][r] = mnew;
          float ps = 0.f;
#pragma unroll
          for (int nt = 0; nt < 4; ++nt) {
            float p = exp2f((s[mt][nt][r] - mnew) * Cs);
            s[mt][nt][r] = p;
            ps += p;
          }
          ps += __shfl_xor(ps, 1);
          ps += __shfl_xor(ps, 2);
          ps += __shfl_xor(ps, 4);
          ps += __shfl_xor(ps, 8);
          l_r[mt][r] = l_r[mt][r] * alpha + ps;
#pragma unroll
          for (int nt = 0; nt < 8; ++nt) o[mt][nt][r] = o[mt][nt][r] * alpha;
        }
      }
      // P -> per-wave LDS (C-layout -> A-fragment layout round trip)
      unsigned short* pw = &Ps[w][0];
#pragma unroll
      for (int mt = 0; mt < 2; ++mt)
#pragma unroll
        for (int r = 0; r < 4; ++r) {
          int row = mt * 16 + lg * 4 + r;
#pragma unroll
          for (int nt = 0; nt < 4; ++nt)
            pw[row * 64 + nt * 16 + lc] = f2bf(s[mt][nt][r]);
        }
      asm volatile("s_waitcnt lgkmcnt(0)" ::: "memory");
      // O += P @ V
#pragma unroll
      for (int kk = 0; kk < 2; ++kk) {
        bf16x8 pa[2];
#pragma unroll
        for (int mt = 0; mt < 2; ++mt)
          pa[mt] = *(const bf16x8*)(pw + (mt * 16 + lc) * 64 + kk * 32 + lg * 8);
#pragma unroll
        for (int nt = 0; nt < 8; ++nt) {
          bf16x8 bv = *(const bf16x8*)(Vt + (nt * 16 + lc) * 64 + kk * 32 + lg * 8);
#pragma unroll
          for (int mt = 0; mt < 2; ++mt)
            o[mt][nt] = __builtin_amdgcn_mfma_f32_16x16x32_bf16(pa[mt], bv, o[mt][nt], 0, 0, 0);
        }
      }
    }
  }

  // epilogue: ctx[b, q, h*128 + d] (the inverse "faithful" reshape)
  unsigned short* outp = ctx + (size_t)b * SEQ * EMB + (size_t)h * HDIM;
#pragma unroll
  for (int mt = 0; mt < 2; ++mt)
#pragma unroll
    for (int r = 0; r < 4; ++r) {
      int row = qw + mt * 16 + lg * 4 + r;
      float inv = 1.0f / l_r[mt][r];
#pragma unroll
      for (int nt = 0; nt < 8; ++nt)
        outp[(size_t)row * EMB + nt * 16 + lc] = f2bf(o[mt][nt][r] * inv);
    }
}

extern "C" void kernel_launch(void* const* d_in, const int* in_sizes, int n_in,
                              void* d_out, int out_size, void* d_ws, size_t ws_size,
                              hipStream_t stream) {
  const float* x  = (const float*)d_in[0];
  const float* Wq = (const float*)d_in[1];
  const float* Wk = (const float*)d_in[2];
  const float* Wv = (const float*)d_in[3];
  const float* Wp = (const float*)d_in[4];
  const float* bp = (const float*)d_in[5];

  char* ws = (char*)d_ws;
  // layout: [0,16M) xb (bf16 x), reused as ctx; [16M,24M) W bf16 (recycled);
  //         [24M,40M) Pq; [40M,56M) Pk; [56M,72M) Pv
  unsigned short* xb = (unsigned short*)ws;
  unsigned short* Wb = (unsigned short*)(ws + (size_t)(16u << 20));
  unsigned short* Pq = (unsigned short*)(ws + (size_t)(24u << 20));
  unsigned short* Pk = (unsigned short*)(ws + (size_t)(40u << 20));
  unsigned short* Pv = (unsigned short*)(ws + (size_t)(56u << 20));

  const int nX4 = ROWSM * EMB / 4;  // 2M float4 groups
  const int nW4 = EMB * EMB / 4;    // 1M

  cvt_bf16<<<nX4 / 256, 256, 0, stream>>>(x, xb, nX4);

  dim3 ggrid(EMB / 128, ROWSM / 128);

  cvt_bf16<<<nW4 / 256, 256, 0, stream>>>(Wq, Wb, nW4);
  gemm_nt<0><<<ggrid, 256, 0, stream>>>(xb, Wb, Pq, nullptr, ROWSM, EMB, EMB);
  cvt_bf16<<<nW4 / 256, 256, 0, stream>>>(Wk, Wb, nW4);
  gemm_nt<0><<<ggrid, 256, 0, stream>>>(xb, Wb, Pk, nullptr, ROWSM, EMB, EMB);
  cvt_bf16<<<nW4 / 256, 256, 0, stream>>>(Wv, Wb, nW4);
  gemm_nt<0><<<ggrid, 256, 0, stream>>>(xb, Wb, Pv, nullptr, ROWSM, EMB, EMB);

  attn_causal<<<dim3(SEQ / 128, 32), 256, 0, stream>>>(Pq, Pk, Pv, xb);

  cvt_bf16<<<nW4 / 256, 256, 0, stream>>>(Wp, Wb, nW4);
  gemm_nt<1><<<ggrid, 256, 0, stream>>>(xb, Wb, d_out, bp, ROWSM, EMB, EMB);
}